// Round 7
// baseline (170.057 us; speedup 1.0000x reference)
//
#include <hip/hip_runtime.h>

#define NN 50000
#define TOPK 32
#define IN_C 128
#define OUT_C 64
#define NEG_SLOPE 0.2f
#define BN_EPS 1e-5f

// K1: MFMA, 16 nodes per block
#define K1_BLOCKS (NN / 16)         // 3125
// K2: 64-thread blocks, 8 nodes (one group) per wave; 1024 blocks, each
// processing ~6 consecutive groups, software-pipelined.
#define K2_GROUPS (NN / 8)          // 6250
#define K2_BLOCKS 1024              // 4 blocks/CU (LDS-bound), all co-resident

// workspace layout (floats)
#define WS_XBF   0                       // bf16 x_lin: NN*64*2B
#define WS_AI    (NN * 32)
#define WS_AJ    (WS_AI + NN)
#define WS_SUMS  (WS_AJ + NN)            // 8 replicas x 128

typedef __bf16 bf16x8 __attribute__((ext_vector_type(8)));
typedef float f32x4 __attribute__((ext_vector_type(4)));
union BF8 { unsigned p[4]; bf16x8 v; };

__device__ inline float leaky(float a) { return a >= 0.f ? a : NEG_SLOPE * a; }
__device__ inline float bl(unsigned u) { return __uint_as_float(u << 16); }
__device__ inline float bh(unsigned u) { return __uint_as_float(u & 0xffff0000u); }

// fp32 -> bf16 via compiler cast (lowers to v_cvt_pk_bf16_f32, RNE)
__device__ inline unsigned pk2bf(float lo, float hi) {
    union { __bf16 b[2]; unsigned u; } cv;
    cv.b[0] = (__bf16)lo; cv.b[1] = (__bf16)hi;
    return cv.u;
}
__device__ inline unsigned short f2bf(float f) {
    union { __bf16 b; unsigned short u; } cv;
    cv.b = (__bf16)f;
    return cv.u;
}

// async global->LDS, 16 B per lane; LDS dest = base + lane*16 (HW rule)
__device__ inline void async16(const uint4* g, uint4* l) {
    __builtin_amdgcn_global_load_lds(
        (const __attribute__((address_space(1))) void*)(const void*)g,
        (__attribute__((address_space(3))) void*)(void*)l, 16, 0, 0);
}

// K1: x_lin(bf16) = x @ lin_w^T via MFMA 16x16x32_bf16 + a_i/a_j epilogue.
__global__ __launch_bounds__(256) void k1_mfma(
    const float* __restrict__ x, const float* __restrict__ emb,
    const float* __restrict__ lin_w,
    const float* __restrict__ att_i, const float* __restrict__ att_j,
    const float* __restrict__ att_em_i, const float* __restrict__ att_em_j,
    unsigned short* __restrict__ x_bf, float* __restrict__ a_i,
    float* __restrict__ a_j, float* __restrict__ sums)
{
    __shared__ float redi[16][5], redj[16][5];
    __shared__ float eredi[16][17], eredj[16][17];
    const int tid = threadIdx.x;
    if (blockIdx.x == 0) {
#pragma unroll
        for (int i = 0; i < 4; ++i) sums[tid + i * 256] = 0.f;
    }

    const int lane = tid & 63;
    const int wv = tid >> 6;
    const int quad = lane >> 4;
    const int nn = lane & 15;
    const int base = blockIdx.x * 16;
    const int c = wv * 16 + nn;          // this lane's output channel

    BF8 bfr[4], afr[4];
    {
        const float* wr = lin_w + (size_t)c * IN_C + quad * 8;
        const float* xr = x + (size_t)(base + nn) * IN_C + quad * 8;
#pragma unroll
        for (int s = 0; s < 4; ++s) {
            const float4 wa = *(const float4*)(wr + s * 32);
            const float4 wb = *(const float4*)(wr + s * 32 + 4);
            const float4 xa = *(const float4*)(xr + s * 32);
            const float4 xb = *(const float4*)(xr + s * 32 + 4);
            bfr[s].p[0] = pk2bf(wa.x, wa.y);
            bfr[s].p[1] = pk2bf(wa.z, wa.w);
            bfr[s].p[2] = pk2bf(wb.x, wb.y);
            bfr[s].p[3] = pk2bf(wb.z, wb.w);
            afr[s].p[0] = pk2bf(xa.x, xa.y);
            afr[s].p[1] = pk2bf(xa.z, xa.w);
            afr[s].p[2] = pk2bf(xb.x, xb.y);
            afr[s].p[3] = pk2bf(xb.z, xb.w);
        }
    }

    f32x4 acc = {0.f, 0.f, 0.f, 0.f};
#pragma unroll
    for (int s = 0; s < 4; ++s)
        acc = __builtin_amdgcn_mfma_f32_16x16x32_bf16(afr[s].v, bfr[s].v, acc,
                                                      0, 0, 0);

    const float aic = att_i[c], ajc = att_j[c];
    float pi[4], pj[4];
#pragma unroll
    for (int r = 0; r < 4; ++r) {
        const int node = base + quad * 4 + r;
        x_bf[(size_t)node * OUT_C + c] = f2bf(acc[r]);
        pi[r] = acc[r] * aic;
        pj[r] = acc[r] * ajc;
    }
#pragma unroll
    for (int d = 1; d < 16; d <<= 1) {
#pragma unroll
        for (int r = 0; r < 4; ++r) {
            pi[r] += __shfl_xor(pi[r], d, 64);
            pj[r] += __shfl_xor(pj[r], d, 64);
        }
    }
    if (nn == 0) {
#pragma unroll
        for (int r = 0; r < 4; ++r) {
            redi[quad * 4 + r][wv] = pi[r];
            redj[quad * 4 + r][wv] = pj[r];
        }
    }
    {
        const int nl = tid >> 4, c4 = tid & 15;
        const float4 e4 = ((const float4*)emb)[(size_t)(base + nl) * 16 + c4];
        const float4 i4 = ((const float4*)att_em_i)[c4];
        const float4 j4 = ((const float4*)att_em_j)[c4];
        eredi[nl][c4] = e4.x * i4.x + e4.y * i4.y + e4.z * i4.z + e4.w * i4.w;
        eredj[nl][c4] = e4.x * j4.x + e4.y * j4.y + e4.z * j4.z + e4.w * j4.w;
    }
    __syncthreads();
    if (tid < 16) {
        float si = redi[tid][0] + redi[tid][1] + redi[tid][2] + redi[tid][3];
        float sj = redj[tid][0] + redj[tid][1] + redj[tid][2] + redj[tid][3];
#pragma unroll
        for (int r = 0; r < 16; ++r) { si += eredi[tid][r]; sj += eredj[tid][r]; }
        a_i[base + tid] = si;
        a_j[base + tid] = sj;
    }
}

// K2 v7: round-0 per-group code UNCHANGED (all 33 rows via global_load_lds,
// wbuf weight exchange, sb BN exchange, single vmcnt(0) drain, same
// accumulation order) — wrapped in a multi-group software pipeline:
// each of 1024 blocks (4/CU, all co-resident) processes ~6 consecutive
// groups; next group's src row + a_i/a_j load during the current consume,
// next gathers issue right after consume so their flight hides under the
// next softmax. Distinguishes latency-regime (big win) from BW-regime
// (neutral) with zero structural risk to the per-group code.
__global__ __launch_bounds__(64) void k2_attn(
    const int* __restrict__ src, const uint4* __restrict__ x_bf4,
    const float* __restrict__ a_j, const float* __restrict__ a_i,
    const float* __restrict__ bias, float* __restrict__ out,
    float* __restrict__ sums)
{
    __shared__ uint4 stage[33 * 64];     // 33 KB staged rows
    __shared__ float wbuf[8][36];        // per-node 33 weights (+pad)
    __shared__ float sb1[64][9], sb2[64][9];

    const int tid = threadIdx.x;         // == lane (64-thread block)
    const int g = tid >> 3;              // node within group of 8
    const int q = tid & 7;               // row slice
    const int b = blockIdx.x;

    // contiguous chunks: blocks 0..105 get 7 groups, the rest 6 (total 6250)
    int gi = b * 6 + (b < 106 ? b : 106);
    const int gend = gi + (b < 106 ? 7 : 6);

    int t = gi * 8 + g;

    // ---- prologue: prefetch group gi (round-0 order: a_j before gathers) --
    {
        const int4* sp4 = (const int4*)(src + (size_t)t * TOPK);
        int4 s4[8];
#pragma unroll
        for (int i = 0; i < 8; ++i) s4[i] = sp4[i];
        int4 sq = sp4[q];
        float ai_t = a_i[t], ajs = a_j[t];
        float aj0 = a_j[sq.x], aj1 = a_j[sq.y], aj2 = a_j[sq.z], aj3 = a_j[sq.w];

#pragma unroll
        for (int i = 0; i < 8; ++i) {
            async16(x_bf4 + ((size_t)s4[i].x * 8 + q), &stage[(i * 4 + 0) * 64]);
            async16(x_bf4 + ((size_t)s4[i].y * 8 + q), &stage[(i * 4 + 1) * 64]);
            async16(x_bf4 + ((size_t)s4[i].z * 8 + q), &stage[(i * 4 + 2) * 64]);
            async16(x_bf4 + ((size_t)s4[i].w * 8 + q), &stage[(i * 4 + 3) * 64]);
        }
        async16(x_bf4 + ((size_t)t * 8 + q), &stage[32 * 64]);   // self row

        for (;;) {
            // ---- 1. softmax for current group (waits a_j, gathers fly) ----
            float l0 = leaky(ai_t + aj0);
            float l1 = leaky(ai_t + aj1);
            float l2 = leaky(ai_t + aj2);
            float l3 = leaky(ai_t + aj3);
            const float ls = leaky(ai_t + ajs);
            float mx = fmaxf(fmaxf(l0, l1), fmaxf(l2, l3));
#pragma unroll
            for (int d = 1; d < 8; d <<= 1) mx = fmaxf(mx, __shfl_xor(mx, d, 64));
            mx = fmaxf(mx, ls);
            const float e0 = __expf(l0 - mx), e1 = __expf(l1 - mx);
            const float e2 = __expf(l2 - mx), e3 = __expf(l3 - mx);
            const float es = __expf(ls - mx);
            float den = (e0 + e1) + (e2 + e3);
#pragma unroll
            for (int d = 1; d < 8; d <<= 1) den += __shfl_xor(den, d, 64);
            den += es + 1e-16f;
            const float inv = 1.f / den;

            ((float4*)&wbuf[g][q * 4])[0] =
                make_float4(e0 * inv, e1 * inv, e2 * inv, e3 * inv);
            if (q == 0) wbuf[g][32] = es * inv;
            __syncthreads();              // single wave: cheap

            float4 w4[8];
#pragma unroll
            for (int i = 0; i < 8; ++i) w4[i] = ((const float4*)wbuf[g])[i];
            const float wself = wbuf[g][32];

            __builtin_amdgcn_s_waitcnt(0x0F70);   // vmcnt(0): rows resident
            __syncthreads();

            // ---- 2. prefetch NEXT group's indices + logit inputs (in
            //         flight during the consume below) ----
            const bool more = (gi + 1 < gend);
            const int tn = t + 8;
            if (more) {
                const int4* np4 = (const int4*)(src + (size_t)tn * TOPK);
#pragma unroll
                for (int i = 0; i < 8; ++i) s4[i] = np4[i];
                sq   = np4[q];
                ai_t = a_i[tn];
                ajs  = a_j[tn];
            }

            // ---- 3. consume 33 staged rows (round-0 loop, order e=0..32) --
            float A[8];
#pragma unroll
            for (int j = 0; j < 8; ++j) A[j] = 0.f;
#pragma unroll
            for (int e = 0; e < 33; ++e) {
                const uint4 u = stage[e * 64 + tid];
                const float w =
                    (e < 32) ? ((const float*)&w4[e >> 2])[e & 3] : wself;
                A[0] = fmaf(w, bl(u.x), A[0]); A[1] = fmaf(w, bh(u.x), A[1]);
                A[2] = fmaf(w, bl(u.y), A[2]); A[3] = fmaf(w, bh(u.y), A[3]);
                A[4] = fmaf(w, bl(u.z), A[4]); A[5] = fmaf(w, bh(u.z), A[5]);
                A[6] = fmaf(w, bl(u.w), A[6]); A[7] = fmaf(w, bh(u.w), A[7]);
            }
            const float4 b0 = ((const float4*)bias)[q * 2];
            const float4 b1 = ((const float4*)bias)[q * 2 + 1];
            float v[8];
            v[0] = A[0] + b0.x; v[1] = A[1] + b0.y;
            v[2] = A[2] + b0.z; v[3] = A[3] + b0.w;
            v[4] = A[4] + b1.x; v[5] = A[5] + b1.y;
            v[6] = A[6] + b1.z; v[7] = A[7] + b1.w;
            float4* o4 = (float4*)(out + (size_t)t * OUT_C + q * 8);
            o4[0] = make_float4(v[0], v[1], v[2], v[3]);
            o4[1] = make_float4(v[4], v[5], v[6], v[7]);

            // BN partials: channel c = q*8+j, reduce over the 8 nodes
#pragma unroll
            for (int j = 0; j < 8; ++j) {
                sb1[q * 8 + j][g] = v[j];
                sb2[q * 8 + j][g] = v[j] * v[j];
            }
            __syncthreads();
            {
                float t1 = 0.f, t2 = 0.f;
#pragma unroll
                for (int r = 0; r < 8; ++r) { t1 += sb1[tid][r]; t2 += sb2[tid][r]; }
                float* rep = sums + (gi & 7) * 128;
                atomicAdd(&rep[tid], t1);
                atomicAdd(&rep[64 + tid], t2);
            }

            if (!more) break;

            // ---- 4. issue next group: a_j loads first, then 33 gathers ----
            __syncthreads();             // stage/wbuf WAR guard
            aj0 = a_j[sq.x]; aj1 = a_j[sq.y];
            aj2 = a_j[sq.z]; aj3 = a_j[sq.w];
#pragma unroll
            for (int i = 0; i < 8; ++i) {
                async16(x_bf4 + ((size_t)s4[i].x * 8 + q), &stage[(i * 4 + 0) * 64]);
                async16(x_bf4 + ((size_t)s4[i].y * 8 + q), &stage[(i * 4 + 1) * 64]);
                async16(x_bf4 + ((size_t)s4[i].z * 8 + q), &stage[(i * 4 + 2) * 64]);
                async16(x_bf4 + ((size_t)s4[i].w * 8 + q), &stage[(i * 4 + 3) * 64]);
            }
            async16(x_bf4 + ((size_t)tn * 8 + q), &stage[32 * 64]);  // self
            t = tn;
            ++gi;
        }
    }
}

// K4: BN stats from the 8 sum replicas (redundant per block), apply + ReLU.
__global__ __launch_bounds__(256) void k4_bn(
    float* __restrict__ out, const float* __restrict__ sums,
    const float* __restrict__ gamma, const float* __restrict__ beta)
{
    __shared__ float s_sc[64], s_sh[64];
    const int tid = threadIdx.x;
    if (tid < 64) {
        float s1 = 0.f, s2 = 0.f;
#pragma unroll
        for (int r = 0; r < 8; ++r) {
            s1 += sums[r * 128 + tid];
            s2 += sums[r * 128 + 64 + tid];
        }
        const float mu = s1 / (float)NN;
        const float ex2 = s2 / (float)NN;
        const float var = fmaxf(ex2 - mu * mu, 0.f);
        const float sc = gamma[tid] / sqrtf(var + BN_EPS);
        s_sc[tid] = sc;
        s_sh[tid] = beta[tid] - mu * sc;
    }
    __syncthreads();
    const int total = NN * OUT_C / 4;
    float4* p = (float4*)out;
    for (int idx = blockIdx.x * 256 + tid; idx < total; idx += gridDim.x * 256) {
        float4 v = p[idx];
        const int c0 = (idx & 15) * 4;
        v.x = fmaxf(fmaf(v.x, s_sc[c0 + 0], s_sh[c0 + 0]), 0.f);
        v.y = fmaxf(fmaf(v.y, s_sc[c0 + 1], s_sh[c0 + 1]), 0.f);
        v.z = fmaxf(fmaf(v.z, s_sc[c0 + 2], s_sh[c0 + 2]), 0.f);
        v.w = fmaxf(fmaf(v.w, s_sc[c0 + 3], s_sh[c0 + 3]), 0.f);
        p[idx] = v;
    }
}

extern "C" void kernel_launch(void* const* d_in, const int* in_sizes, int n_in,
                              void* d_out, int out_size, void* d_ws, size_t ws_size,
                              hipStream_t stream) {
    const float* x        = (const float*)d_in[0];
    const float* emb      = (const float*)d_in[1];
    const int*   edge     = (const int*)d_in[2];   // row 0 = src
    const float* lin_w    = (const float*)d_in[3];
    const float* att_i    = (const float*)d_in[4];
    const float* att_j    = (const float*)d_in[5];
    const float* att_em_i = (const float*)d_in[6];
    const float* att_em_j = (const float*)d_in[7];
    const float* bias     = (const float*)d_in[8];
    const float* gamma    = (const float*)d_in[9];
    const float* beta     = (const float*)d_in[10];

    float* ws    = (float*)d_ws;
    unsigned short* x_bf = (unsigned short*)(ws + WS_XBF);
    float* a_i   = ws + WS_AI;
    float* a_j   = ws + WS_AJ;
    float* sums  = ws + WS_SUMS;
    float* out   = (float*)d_out;

    k1_mfma<<<K1_BLOCKS, 256, 0, stream>>>(x, emb, lin_w, att_i, att_j,
                                           att_em_i, att_em_j, x_bf, a_i, a_j, sums);
    k2_attn<<<K2_BLOCKS, 64, 0, stream>>>(edge, (const uint4*)x_bf, a_j, a_i,
                                          bias, out, sums);
    k4_bn<<<1024, 256, 0, stream>>>(out, sums, gamma, beta);
}

// Round 8
// 163.827 us; speedup vs baseline: 1.0380x; 1.0380x over previous
//
#include <hip/hip_runtime.h>

#define NN 50000
#define TOPK 32
#define IN_C 128
#define OUT_C 64
#define NEG_SLOPE 0.2f
#define BN_EPS 1e-5f

// K1: MFMA, 16 nodes per block
#define K1_BLOCKS (NN / 16)         // 3125
// K2: 64-thread blocks, 1 wave = 8 nodes (8 lanes x 16B = full row)
#define K2_BLOCKS (NN / 8)          // 6250

// workspace layout (floats)
#define WS_XBF   0                       // bf16 x_lin: NN*64*2B
#define WS_AI    (NN * 32)
#define WS_AJ    (WS_AI + NN)
#define WS_SUMS  (WS_AJ + NN)            // 8 replicas x 128

typedef __bf16 bf16x8 __attribute__((ext_vector_type(8)));
typedef float f32x4 __attribute__((ext_vector_type(4)));
union BF8 { unsigned p[4]; bf16x8 v; };

__device__ inline float leaky(float a) { return a >= 0.f ? a : NEG_SLOPE * a; }
__device__ inline float bl(unsigned u) { return __uint_as_float(u << 16); }
__device__ inline float bh(unsigned u) { return __uint_as_float(u & 0xffff0000u); }

// fp32 -> bf16 via compiler cast (lowers to v_cvt_pk_bf16_f32, RNE — same
// rounding as the manual sequence; kept from R1, neutral across R1-R7)
__device__ inline unsigned pk2bf(float lo, float hi) {
    union { __bf16 b[2]; unsigned u; } cv;
    cv.b[0] = (__bf16)lo; cv.b[1] = (__bf16)hi;
    return cv.u;
}
__device__ inline unsigned short f2bf(float f) {
    union { __bf16 b; unsigned short u; } cv;
    cv.b = (__bf16)f;
    return cv.u;
}

// async global->LDS, 16 B per lane; LDS dest = base + lane*16 (HW rule)
__device__ inline void async16(const uint4* g, uint4* l) {
    __builtin_amdgcn_global_load_lds(
        (const __attribute__((address_space(1))) void*)(const void*)g,
        (__attribute__((address_space(3))) void*)(void*)l, 16, 0, 0);
}

// K1: x_lin(bf16) = x @ lin_w^T via MFMA 16x16x32_bf16 + a_i/a_j epilogue.
__global__ __launch_bounds__(256) void k1_mfma(
    const float* __restrict__ x, const float* __restrict__ emb,
    const float* __restrict__ lin_w,
    const float* __restrict__ att_i, const float* __restrict__ att_j,
    const float* __restrict__ att_em_i, const float* __restrict__ att_em_j,
    unsigned short* __restrict__ x_bf, float* __restrict__ a_i,
    float* __restrict__ a_j, float* __restrict__ sums)
{
    __shared__ float redi[16][5], redj[16][5];
    __shared__ float eredi[16][17], eredj[16][17];
    const int tid = threadIdx.x;
    if (blockIdx.x == 0) {
#pragma unroll
        for (int i = 0; i < 4; ++i) sums[tid + i * 256] = 0.f;
    }

    const int lane = tid & 63;
    const int wv = tid >> 6;
    const int quad = lane >> 4;
    const int nn = lane & 15;
    const int base = blockIdx.x * 16;
    const int c = wv * 16 + nn;          // this lane's output channel

    BF8 bfr[4], afr[4];
    {
        const float* wr = lin_w + (size_t)c * IN_C + quad * 8;
        const float* xr = x + (size_t)(base + nn) * IN_C + quad * 8;
#pragma unroll
        for (int s = 0; s < 4; ++s) {
            const float4 wa = *(const float4*)(wr + s * 32);
            const float4 wb = *(const float4*)(wr + s * 32 + 4);
            const float4 xa = *(const float4*)(xr + s * 32);
            const float4 xb = *(const float4*)(xr + s * 32 + 4);
            bfr[s].p[0] = pk2bf(wa.x, wa.y);
            bfr[s].p[1] = pk2bf(wa.z, wa.w);
            bfr[s].p[2] = pk2bf(wb.x, wb.y);
            bfr[s].p[3] = pk2bf(wb.z, wb.w);
            afr[s].p[0] = pk2bf(xa.x, xa.y);
            afr[s].p[1] = pk2bf(xa.z, xa.w);
            afr[s].p[2] = pk2bf(xb.x, xb.y);
            afr[s].p[3] = pk2bf(xb.z, xb.w);
        }
    }

    f32x4 acc = {0.f, 0.f, 0.f, 0.f};
#pragma unroll
    for (int s = 0; s < 4; ++s)
        acc = __builtin_amdgcn_mfma_f32_16x16x32_bf16(afr[s].v, bfr[s].v, acc,
                                                      0, 0, 0);

    const float aic = att_i[c], ajc = att_j[c];
    float pi[4], pj[4];
#pragma unroll
    for (int r = 0; r < 4; ++r) {
        const int node = base + quad * 4 + r;
        x_bf[(size_t)node * OUT_C + c] = f2bf(acc[r]);
        pi[r] = acc[r] * aic;
        pj[r] = acc[r] * ajc;
    }
#pragma unroll
    for (int d = 1; d < 16; d <<= 1) {
#pragma unroll
        for (int r = 0; r < 4; ++r) {
            pi[r] += __shfl_xor(pi[r], d, 64);
            pj[r] += __shfl_xor(pj[r], d, 64);
        }
    }
    if (nn == 0) {
#pragma unroll
        for (int r = 0; r < 4; ++r) {
            redi[quad * 4 + r][wv] = pi[r];
            redj[quad * 4 + r][wv] = pj[r];
        }
    }
    {
        const int nl = tid >> 4, c4 = tid & 15;
        const float4 e4 = ((const float4*)emb)[(size_t)(base + nl) * 16 + c4];
        const float4 i4 = ((const float4*)att_em_i)[c4];
        const float4 j4 = ((const float4*)att_em_j)[c4];
        eredi[nl][c4] = e4.x * i4.x + e4.y * i4.y + e4.z * i4.z + e4.w * i4.w;
        eredj[nl][c4] = e4.x * j4.x + e4.y * j4.y + e4.z * j4.z + e4.w * j4.w;
    }
    __syncthreads();
    if (tid < 16) {
        float si = redi[tid][0] + redi[tid][1] + redi[tid][2] + redi[tid][3];
        float sj = redj[tid][0] + redj[tid][1] + redj[tid][2] + redj[tid][3];
#pragma unroll
        for (int r = 0; r < 16; ++r) { si += eredi[tid][r]; sj += eredj[tid][r]; }
        a_i[base + tid] = si;
        a_j[base + tid] = sj;
    }
}

// K2: EXACT round-0 kernel (verified: 161.7/164.1 totals; ~40 us). One wave
// per block, 8 nodes per wave (lane = g*8+q: node g, 16B row slice q). All
// 33 row-gathers issued as global_load_lds (no VGPR dest -> all in flight
// at once), one vmcnt(0) drain, then consume from LDS. Softmax 8-lane
// partitioned; weights cross lanes via small LDS buffer (NOT shfl — the
// shfl-in-consume variants R2-R5 were all 4x slower). BN partials
// atomicAdd to 1-of-8 sum replicas.
// R7 post-mortem: multi-group pipelining regressed (46 us) — k2 is
// gather-throughput-bound (211 MB random gathers, 83% of the 33-us stream
// bound); the 4 staggered blocks/CU already provide the latency hiding.
__global__ __launch_bounds__(64) void k2_attn(
    const int* __restrict__ src, const uint4* __restrict__ x_bf4,
    const float* __restrict__ a_j, const float* __restrict__ a_i,
    const float* __restrict__ bias, float* __restrict__ out,
    float* __restrict__ sums)
{
    __shared__ uint4 stage[33 * 64];     // 33 KB staged rows
    __shared__ float wbuf[8][36];        // per-node 33 weights (+pad)
    __shared__ float sb1[64][9], sb2[64][9];

    const int tid = threadIdx.x;         // == lane (64-thread block)
    const int g = tid >> 3;              // node within group of 8
    const int q = tid & 7;               // row slice
    const int t = blockIdx.x * 8 + g;

    // all 32 src indices of this lane's node (broadcast across its 8 lanes)
    const int4* sp4 = (const int4*)(src + (size_t)t * TOPK);
    int4 s4[8];
#pragma unroll
    for (int i = 0; i < 8; ++i) s4[i] = sp4[i];
    const int4 sq = sp4[q];              // this lane's softmax partition

    // issue all 33 gathers: edge e of each node -> stage[e*64 + lane]
#pragma unroll
    for (int i = 0; i < 8; ++i) {
        async16(x_bf4 + ((size_t)s4[i].x * 8 + q), &stage[(i * 4 + 0) * 64]);
        async16(x_bf4 + ((size_t)s4[i].y * 8 + q), &stage[(i * 4 + 1) * 64]);
        async16(x_bf4 + ((size_t)s4[i].z * 8 + q), &stage[(i * 4 + 2) * 64]);
        async16(x_bf4 + ((size_t)s4[i].w * 8 + q), &stage[(i * 4 + 3) * 64]);
    }
    async16(x_bf4 + ((size_t)t * 8 + q), &stage[32 * 64]);   // self row

    // softmax over 33 edges: lane q owns edges q*4..q*4+3
    const float ai_t = a_i[t];
    float l0 = leaky(ai_t + a_j[sq.x]);
    float l1 = leaky(ai_t + a_j[sq.y]);
    float l2 = leaky(ai_t + a_j[sq.z]);
    float l3 = leaky(ai_t + a_j[sq.w]);
    const float ls = leaky(ai_t + a_j[t]);
    float mx = fmaxf(fmaxf(l0, l1), fmaxf(l2, l3));
#pragma unroll
    for (int d = 1; d < 8; d <<= 1) mx = fmaxf(mx, __shfl_xor(mx, d, 64));
    mx = fmaxf(mx, ls);
    const float e0 = __expf(l0 - mx), e1 = __expf(l1 - mx);
    const float e2 = __expf(l2 - mx), e3 = __expf(l3 - mx);
    const float es = __expf(ls - mx);
    float den = (e0 + e1) + (e2 + e3);
#pragma unroll
    for (int d = 1; d < 8; d <<= 1) den += __shfl_xor(den, d, 64);
    den += es + 1e-16f;
    const float inv = 1.f / den;

    ((float4*)&wbuf[g][q * 4])[0] =
        make_float4(e0 * inv, e1 * inv, e2 * inv, e3 * inv);
    if (q == 0) wbuf[g][32] = es * inv;
    __syncthreads();                      // single wave: cheap

    float4 w4[8];
#pragma unroll
    for (int i = 0; i < 8; ++i) w4[i] = ((const float4*)wbuf[g])[i];
    const float wself = wbuf[g][32];

    __builtin_amdgcn_s_waitcnt(0x0F70);   // vmcnt(0): all staged rows ready
    __syncthreads();

    float A[8];
#pragma unroll
    for (int j = 0; j < 8; ++j) A[j] = 0.f;
#pragma unroll
    for (int e = 0; e < 33; ++e) {
        const uint4 u = stage[e * 64 + tid];
        const float w = (e < 32) ? ((const float*)&w4[e >> 2])[e & 3] : wself;
        A[0] = fmaf(w, bl(u.x), A[0]); A[1] = fmaf(w, bh(u.x), A[1]);
        A[2] = fmaf(w, bl(u.y), A[2]); A[3] = fmaf(w, bh(u.y), A[3]);
        A[4] = fmaf(w, bl(u.z), A[4]); A[5] = fmaf(w, bh(u.z), A[5]);
        A[6] = fmaf(w, bl(u.w), A[6]); A[7] = fmaf(w, bh(u.w), A[7]);
    }
    const float4 b0 = ((const float4*)bias)[q * 2];
    const float4 b1 = ((const float4*)bias)[q * 2 + 1];
    float v[8];
    v[0] = A[0] + b0.x; v[1] = A[1] + b0.y; v[2] = A[2] + b0.z; v[3] = A[3] + b0.w;
    v[4] = A[4] + b1.x; v[5] = A[5] + b1.y; v[6] = A[6] + b1.z; v[7] = A[7] + b1.w;
    float4* o4 = (float4*)(out + (size_t)t * OUT_C + q * 8);
    o4[0] = make_float4(v[0], v[1], v[2], v[3]);
    o4[1] = make_float4(v[4], v[5], v[6], v[7]);

    // BN partials: channel c = q*8+j, reduce over the 8 nodes (col g)
#pragma unroll
    for (int j = 0; j < 8; ++j) {
        sb1[q * 8 + j][g] = v[j];
        sb2[q * 8 + j][g] = v[j] * v[j];
    }
    __syncthreads();
    {
        float t1 = 0.f, t2 = 0.f;
#pragma unroll
        for (int r = 0; r < 8; ++r) { t1 += sb1[tid][r]; t2 += sb2[tid][r]; }
        float* rep = sums + (blockIdx.x & 7) * 128;
        atomicAdd(&rep[tid], t1);
        atomicAdd(&rep[64 + tid], t2);
    }
}

// K4: BN stats from the 8 sum replicas (redundant per block), apply + ReLU.
__global__ __launch_bounds__(256) void k4_bn(
    float* __restrict__ out, const float* __restrict__ sums,
    const float* __restrict__ gamma, const float* __restrict__ beta)
{
    __shared__ float s_sc[64], s_sh[64];
    const int tid = threadIdx.x;
    if (tid < 64) {
        float s1 = 0.f, s2 = 0.f;
#pragma unroll
        for (int r = 0; r < 8; ++r) {
            s1 += sums[r * 128 + tid];
            s2 += sums[r * 128 + 64 + tid];
        }
        const float mu = s1 / (float)NN;
        const float ex2 = s2 / (float)NN;
        const float var = fmaxf(ex2 - mu * mu, 0.f);
        const float sc = gamma[tid] / sqrtf(var + BN_EPS);
        s_sc[tid] = sc;
        s_sh[tid] = beta[tid] - mu * sc;
    }
    __syncthreads();
    const int total = NN * OUT_C / 4;
    float4* p = (float4*)out;
    for (int idx = blockIdx.x * 256 + tid; idx < total; idx += gridDim.x * 256) {
        float4 v = p[idx];
        const int c0 = (idx & 15) * 4;
        v.x = fmaxf(fmaf(v.x, s_sc[c0 + 0], s_sh[c0 + 0]), 0.f);
        v.y = fmaxf(fmaf(v.y, s_sc[c0 + 1], s_sh[c0 + 1]), 0.f);
        v.z = fmaxf(fmaf(v.z, s_sc[c0 + 2], s_sh[c0 + 2]), 0.f);
        v.w = fmaxf(fmaf(v.w, s_sc[c0 + 3], s_sh[c0 + 3]), 0.f);
        p[idx] = v;
    }
}

extern "C" void kernel_launch(void* const* d_in, const int* in_sizes, int n_in,
                              void* d_out, int out_size, void* d_ws, size_t ws_size,
                              hipStream_t stream) {
    const float* x        = (const float*)d_in[0];
    const float* emb      = (const float*)d_in[1];
    const int*   edge     = (const int*)d_in[2];   // row 0 = src
    const float* lin_w    = (const float*)d_in[3];
    const float* att_i    = (const float*)d_in[4];
    const float* att_j    = (const float*)d_in[5];
    const float* att_em_i = (const float*)d_in[6];
    const float* att_em_j = (const float*)d_in[7];
    const float* bias     = (const float*)d_in[8];
    const float* gamma    = (const float*)d_in[9];
    const float* beta     = (const float*)d_in[10];

    float* ws    = (float*)d_ws;
    unsigned short* x_bf = (unsigned short*)(ws + WS_XBF);
    float* a_i   = ws + WS_AI;
    float* a_j   = ws + WS_AJ;
    float* sums  = ws + WS_SUMS;
    float* out   = (float*)d_out;

    k1_mfma<<<K1_BLOCKS, 256, 0, stream>>>(x, emb, lin_w, att_i, att_j,
                                           att_em_i, att_em_j, x_bf, a_i, a_j, sums);
    k2_attn<<<K2_BLOCKS, 64, 0, stream>>>(edge, (const uint4*)x_bf, a_j, a_i,
                                          bias, out, sums);
    k4_bn<<<1024, 256, 0, stream>>>(out, sums, gamma, beta);
}